// Round 16
// baseline (3144.261 us; speedup 1.0000x reference)
//
#include <hip/hip_runtime.h>
#include <hip/hip_bf16.h>
#include <math.h>

// Problem constants
constexpr int BATCH = 8;
constexpr int NPTS  = 2048;
constexpr int CH    = 128;
constexpr int CHO   = 256;
constexpr int NCEN  = 512;
constexpr int NNEI  = 32;   // n_near
constexpr int NTOP  = 11;   // n_stepk + 1
constexpr int NW    = 64;   // bitset words per row (2048/32)
constexpr int SMEM_BYTES = 17408;

struct Ptr7 { const float* p[7]; };

// ---------------------------------------------------------------- xx = sum(x^2)
__global__ __launch_bounds__(256) void xx_kernel(const float* __restrict__ x,
                                                 float* __restrict__ xx) {
    int p = blockIdx.x * 256 + threadIdx.x;
    if (p >= BATCH * NPTS) return;
    const float4* xr = (const float4*)(x + (size_t)p * CH);
    float s = 0.f;
#pragma unroll
    for (int i = 0; i < CH / 4; i++) {
        float4 v = xr[i];
        s += v.x * v.x + v.y * v.y + v.z * v.z + v.w * v.w;
    }
    xx[p] = s;
}

// ---------------------------------------------------------------- D = xx_i + xx_j - 2*dot  (symmetric: jt>=it only, mirrored)
__global__ __launch_bounds__(256) void dmat_kernel(const float* __restrict__ x,
                                                   const float* __restrict__ xx,
                                                   float* __restrict__ D) {
    __shared__ __align__(16) char smem[SMEM_BYTES];
    int it = blockIdx.y, jt = blockIdx.x;
    if (jt < it) return;                       // symmetry: skip lower-triangle tiles
    float (*As)[68] = (float(*)[68])smem;
    float (*Bs)[68] = (float(*)[68])(smem + 32 * 68 * 4);
    int bz = blockIdx.z;
    int i0 = it * 64, j0 = jt * 64;
    const float* X = x + (size_t)bz * NPTS * CH;
    int t = threadIdx.x, tx = t & 15, ty = t >> 4;
    int lr = t >> 3, lc = (t & 7) * 4;
    const float* ai0 = X + (size_t)(i0 + lr) * CH;
    const float* ai1 = X + (size_t)(i0 + lr + 32) * CH;
    const float* bj0 = X + (size_t)(j0 + lr) * CH;
    const float* bj1 = X + (size_t)(j0 + lr + 32) * CH;
    float acc[4][4] = {};
    for (int kc = 0; kc < CH; kc += 32) {
        float4 a0 = *(const float4*)(ai0 + kc + lc);
        float4 a1 = *(const float4*)(ai1 + kc + lc);
        float4 b0 = *(const float4*)(bj0 + kc + lc);
        float4 b1 = *(const float4*)(bj1 + kc + lc);
        __syncthreads();
        As[lc + 0][lr] = a0.x; As[lc + 1][lr] = a0.y; As[lc + 2][lr] = a0.z; As[lc + 3][lr] = a0.w;
        As[lc + 0][lr + 32] = a1.x; As[lc + 1][lr + 32] = a1.y; As[lc + 2][lr + 32] = a1.z; As[lc + 3][lr + 32] = a1.w;
        Bs[lc + 0][lr] = b0.x; Bs[lc + 1][lr] = b0.y; Bs[lc + 2][lr] = b0.z; Bs[lc + 3][lr] = b0.w;
        Bs[lc + 0][lr + 32] = b1.x; Bs[lc + 1][lr + 32] = b1.y; Bs[lc + 2][lr + 32] = b1.z; Bs[lc + 3][lr + 32] = b1.w;
        __syncthreads();
#pragma unroll
        for (int kk = 0; kk < 32; kk++) {
            float4 av = *(const float4*)&As[kk][ty * 4];
            float4 bv = *(const float4*)&Bs[kk][tx * 4];
            float a[4] = {av.x, av.y, av.z, av.w};
            float b[4] = {bv.x, bv.y, bv.z, bv.w};
#pragma unroll
            for (int i = 0; i < 4; i++)
#pragma unroll
                for (int j = 0; j < 4; j++) acc[i][j] += a[i] * b[j];
        }
    }
    const float* xxb = xx + bz * NPTS;
    float xi[4], xj[4];
#pragma unroll
    for (int i = 0; i < 4; i++) xi[i] = xxb[i0 + ty * 4 + i];
#pragma unroll
    for (int j = 0; j < 4; j++) xj[j] = xxb[j0 + tx * 4 + j];
    float ov[4][4];
#pragma unroll
    for (int i = 0; i < 4; i++)
#pragma unroll
        for (int j = 0; j < 4; j++) ov[i][j] = xi[i] + xj[j] - 2.f * acc[i][j];
    // normal tile write
#pragma unroll
    for (int i = 0; i < 4; i++) {
        float4 o = {ov[i][0], ov[i][1], ov[i][2], ov[i][3]};
        *(float4*)(D + ((size_t)bz * NPTS + i0 + ty * 4 + i) * NPTS + j0 + tx * 4) = o;
    }
    if (jt > it) {
        // mirrored tile write via LDS restage (values bitwise identical by commutativity)
        __syncthreads();
        float (*T)[65] = (float(*)[65])smem;
#pragma unroll
        for (int i = 0; i < 4; i++)
#pragma unroll
            for (int j = 0; j < 4; j++) T[ty * 4 + i][tx * 4 + j] = ov[i][j];
        __syncthreads();
#pragma unroll
        for (int i = 0; i < 4; i++) {
            float4 o;
            o.x = T[tx * 4 + 0][ty * 4 + i];
            o.y = T[tx * 4 + 1][ty * 4 + i];
            o.z = T[tx * 4 + 2][ty * 4 + i];
            o.w = T[tx * 4 + 3][ty * 4 + i];
            *(float4*)(D + ((size_t)bz * NPTS + j0 + ty * 4 + i) * NPTS + i0 + tx * 4) = o;
        }
    }
}

// ---------------------------------------------------------------- fused front: fps (blocks 0..7) + top-11 (blocks 8..)
__global__ __launch_bounds__(256) void fused_front_kernel(const float* __restrict__ D,
                                                          unsigned int* __restrict__ adj,
                                                          int* __restrict__ fps_idx) {
    __shared__ __align__(16) char smem[SMEM_BYTES];
    if (blockIdx.x < BATCH) {
        // ---------------- FPS: one wave; row staged via global_load_lds; broadcast-scan reduce ----------------
        int lane = threadIdx.x;
        if (lane >= 64) return;
        int b = blockIdx.x;
        float* row_lds = (float*)smem;                 // 2048 floats (8 KB)
        float2* red = (float2*)(smem + 8192);          // 64 pairs (512 B)
        float mind[32];
#pragma unroll
        for (int r = 0; r < 32; r++) mind[r] = INFINITY;
        int prev = 0;
        if (lane == 0) fps_idx[b * NCEN] = 0;
        const float* Db = D + (size_t)b * NPTS * NPTS;
        for (int s = 1; s < NCEN; s++) {
            const float* rowg = Db + (size_t)prev * NPTS;
            // 8 register-free DMA loads -> LDS; issue back-to-back
#pragma unroll
            for (int k = 0; k < 8; k++) {
                __builtin_amdgcn_global_load_lds(
                    (const __attribute__((address_space(1))) unsigned int*)(rowg + 4 * (lane + 64 * k)),
                    (__attribute__((address_space(3))) unsigned int*)(row_lds + 256 * k),
                    16, 0, 0);
            }
            asm volatile("s_waitcnt vmcnt(0)" ::: "memory");
            float bv = -INFINITY; int bj = NPTS;
#pragma unroll
            for (int k = 0; k < 8; k++) {
                float4 g = ((const float4*)row_lds)[lane + 64 * k];
                int j0 = 4 * (lane + 64 * k);
                float m0 = fminf(mind[4 * k + 0], g.x); mind[4 * k + 0] = m0;
                float m1 = fminf(mind[4 * k + 1], g.y); mind[4 * k + 1] = m1;
                float m2 = fminf(mind[4 * k + 2], g.z); mind[4 * k + 2] = m2;
                float m3 = fminf(mind[4 * k + 3], g.w); mind[4 * k + 3] = m3;
                if (m0 > bv) { bv = m0; bj = j0 + 0; }
                if (m1 > bv) { bv = m1; bj = j0 + 1; }
                if (m2 > bv) { bv = m2; bj = j0 + 2; }
                if (m3 > bv) { bv = m3; bj = j0 + 3; }
            }
            // broadcast-scan reduce: all lanes scan 64 (v,idx) pairs, explicit index tie-break
            red[lane] = make_float2(bv, __int_as_float(bj));
            float cv[4]; int cj[4];
#pragma unroll
            for (int c = 0; c < 4; c++) {
                float v = -INFINITY; int j = NPTS;
#pragma unroll
                for (int k = 0; k < 16; k++) {
                    float2 e = red[c * 16 + k];
                    int ej = __float_as_int(e.y);
                    if (e.x > v || (e.x == v && ej < j)) { v = e.x; j = ej; }
                }
                cv[c] = v; cj[c] = j;
            }
            float bestv = cv[0]; int bestj = cj[0];
#pragma unroll
            for (int c = 1; c < 4; c++)
                if (cv[c] > bestv || (cv[c] == bestv && cj[c] < bestj)) { bestv = cv[c]; bestj = cj[c]; }
            if (lane == 0) fps_idx[b * NCEN + s] = bestj;
            prev = bestj;   // identical on all lanes
        }
        return;
    }
    // ---------------- top-11 ----------------
    float* row = (float*)smem;
    float* rv = row + NPTS;
    int* ri = (int*)(rv + 256);
    int* picks = ri + 256;
    int rid = blockIdx.x - BATCH;
    const float* Dr = D + (size_t)rid * NPTS;
    int t = threadIdx.x;
    float4* rp = (float4*)row;
    rp[t] = ((const float4*)Dr)[t];
    rp[t + 256] = ((const float4*)Dr)[t + 256];
    __syncthreads();
    for (int it = 0; it < NTOP; it++) {
        float bv = row[t];
        int bi = t;
#pragma unroll
        for (int k = 1; k < 8; k++) {
            int j = t + (k << 8);
            float v = row[j];
            if (v < bv) { bv = v; bi = j; }
        }
        rv[t] = bv; ri[t] = bi;
        __syncthreads();
        for (int off = 128; off > 0; off >>= 1) {
            if (t < off) {
                float ovv = rv[t + off]; int oi = ri[t + off];
                if (ovv < rv[t] || (ovv == rv[t] && oi < ri[t])) { rv[t] = ovv; ri[t] = oi; }
            }
            __syncthreads();
        }
        if (t == 0) { picks[it] = ri[0]; row[ri[0]] = INFINITY; }
        __syncthreads();
    }
    if (t < NW) {
        unsigned w = 0;
#pragma unroll
        for (int p = 0; p < NTOP; p++) {
            int j = picks[p];
            if ((j >> 5) == t) w |= 1u << (j & 31);
        }
        adj[(size_t)rid * NW + t] = w;
    }
}

// ---------------------------------------------------------------- gather indices
__global__ void make_gather(const int* __restrict__ fps_idx, int* __restrict__ gatherC) {
    int r = blockIdx.x * 256 + threadIdx.x;
    if (r >= BATCH * NCEN) return;
    int b = r >> 9, s = r & 511;
    gatherC[r] = b * NPTS + fps_idx[b * NCEN + s];
}

// ---------------------------------------------------------------- 2-hop reach + top-32 on fp32 D
__global__ __launch_bounds__(256) void reach_top32_kernel(const unsigned int* __restrict__ adj,
                                                          const float* __restrict__ D,
                                                          const int* __restrict__ fps_idx,
                                                          int* __restrict__ idx_sel) {
    __shared__ unsigned adjw[NW], R1[NW], R2[NW];
    __shared__ int lst[NPTS];
    __shared__ float dst[NPTS];
    __shared__ int cnt;
    __shared__ float rv[256];
    __shared__ int rj[256], rp[256];
    __shared__ int sel[NNEI];
    int s = blockIdx.x, b = blockIdx.y, t = threadIdx.x;
    int i = fps_idx[b * NCEN + s];
    const unsigned* arow = adj + ((size_t)(b * NPTS + i)) * NW;
    if (t < NW) { adjw[t] = arow[t]; R1[t] = arow[t]; }
    if (t == 0) cnt = 0;
    __syncthreads();
    if (t < NW) {
        unsigned w = adjw[t];
        while (w) { int bb = __ffs(w) - 1; w &= w - 1; int p = atomicAdd(&cnt, 1); lst[p] = t * 32 + bb; }
    }
    __syncthreads();
    int n1 = cnt;
    {
        int g = t >> 6, lane = t & 63;
        for (int p = g; p < n1; p += 4) {
            unsigned aw = adj[((size_t)(b * NPTS + lst[p])) * NW + lane];
            atomicOr(&R1[lane], aw);
        }
    }
    __syncthreads();
    if (t == 0) cnt = 0;
    __syncthreads();
    if (t < NW) {
        unsigned w = R1[t];
        while (w) { int bb = __ffs(w) - 1; w &= w - 1; int p = atomicAdd(&cnt, 1); lst[p] = t * 32 + bb; }
        R2[t] = adjw[t];
    }
    __syncthreads();
    int n2 = cnt;
    {
        int g = t >> 6, lane = t & 63;
        for (int p = g; p < n2; p += 4) {
            unsigned aw = adj[((size_t)(b * NPTS + lst[p])) * NW + lane];
            atomicOr(&R2[lane], aw);
        }
    }
    __syncthreads();
    if (t == 0) cnt = 0;
    __syncthreads();
    const float* Dr = D + (size_t)(b * NPTS + i) * NPTS;
    if (t < NW) {
        unsigned w = R2[t];
        while (w) {
            int bb = __ffs(w) - 1; w &= w - 1;
            int j = t * 32 + bb;
            int p = atomicAdd(&cnt, 1);
            lst[p] = j; dst[p] = Dr[j];
        }
    }
    __syncthreads();
    int L = cnt;
    int nsel = L < NNEI ? L : NNEI;
    for (int r = 0; r < nsel; r++) {
        float bv = INFINITY; int bj = 0x7fffffff, bp = -1;
        for (int p = t; p < L; p += 256) {
            float v = dst[p]; int j = lst[p];
            if (v < bv || (v == bv && j < bj)) { bv = v; bj = j; bp = p; }
        }
        rv[t] = bv; rj[t] = bj; rp[t] = bp;
        __syncthreads();
        for (int off = 128; off > 0; off >>= 1) {
            if (t < off) {
                if (rv[t + off] < rv[t] || (rv[t + off] == rv[t] && rj[t + off] < rj[t])) {
                    rv[t] = rv[t + off]; rj[t] = rj[t + off]; rp[t] = rp[t + off];
                }
            }
            __syncthreads();
        }
        if (t == 0) { sel[r] = rj[0]; dst[rp[0]] = INFINITY; }
        __syncthreads();
    }
    if (t == 0 && nsel < NNEI) {
        int r = nsel;
        for (int j = 0; j < NPTS && r < NNEI; j++)
            if (!((R2[j >> 5] >> (j & 31)) & 1)) sel[r++] = j;
    }
    __syncthreads();
    if (t < NNEI) idx_sel[((size_t)(b * NCEN + s)) * NNEI + t] = sel[t];
}

// ---------------------------------------------------------------- 64x64 fp32 GEMM tile (smem arena)
template <int KSIZE, bool RELU>
__device__ __forceinline__ void gemm_tile64(char* smem,
                                            const float* __restrict__ A, int lda,
                                            const int* __restrict__ gather,
                                            const float* __restrict__ W, int ldw,
                                            const float* __restrict__ bias,
                                            float* __restrict__ Out, int ldo) {
    float (*As)[68] = (float(*)[68])smem;
    float (*Ws)[68] = (float(*)[68])(smem + 32 * 68 * 4);
    int t = threadIdx.x;
    int tx = t & 15, ty = t >> 4;
    int lr = t >> 3, lc = (t & 7) * 4;
    const float* ar0 = A + (size_t)(gather ? gather[lr] : lr) * lda;
    const float* ar1 = A + (size_t)(gather ? gather[lr + 32] : lr + 32) * lda;
    float acc[4][4] = {};
    for (int kc = 0; kc < KSIZE; kc += 32) {
        float4 a0 = *(const float4*)(ar0 + kc + lc);
        float4 a1 = *(const float4*)(ar1 + kc + lc);
        float4 w0 = *(const float4*)(W + (size_t)(kc + lr) * ldw + lc);
        float4 w1 = *(const float4*)(W + (size_t)(kc + lr) * ldw + lc + 32);
        __syncthreads();
        As[lc + 0][lr] = a0.x; As[lc + 1][lr] = a0.y; As[lc + 2][lr] = a0.z; As[lc + 3][lr] = a0.w;
        As[lc + 0][lr + 32] = a1.x; As[lc + 1][lr + 32] = a1.y; As[lc + 2][lr + 32] = a1.z; As[lc + 3][lr + 32] = a1.w;
        *(float4*)&Ws[lr][lc] = w0;
        *(float4*)&Ws[lr][lc + 32] = w1;
        __syncthreads();
#pragma unroll
        for (int kk = 0; kk < 32; kk++) {
            float4 av = *(const float4*)&As[kk][ty * 4];
            float4 wv = *(const float4*)&Ws[kk][tx * 4];
            float a[4] = {av.x, av.y, av.z, av.w};
            float w[4] = {wv.x, wv.y, wv.z, wv.w};
#pragma unroll
            for (int i = 0; i < 4; i++)
#pragma unroll
                for (int j = 0; j < 4; j++) acc[i][j] += a[i] * w[j];
        }
    }
#pragma unroll
    for (int i = 0; i < 4; i++) {
        int r = ty * 4 + i;
        float4 o;
        o.x = acc[i][0] + bias[tx * 4 + 0];
        o.y = acc[i][1] + bias[tx * 4 + 1];
        o.z = acc[i][2] + bias[tx * 4 + 2];
        o.w = acc[i][3] + bias[tx * 4 + 3];
        if (RELU) {
            o.x = fmaxf(o.x, 0.f); o.y = fmaxf(o.y, 0.f);
            o.z = fmaxf(o.z, 0.f); o.w = fmaxf(o.w, 0.f);
        }
        *(float4*)(Out + (size_t)r * ldo + tx * 4) = o;
    }
}

// ---------------------------------------------------------------- GEMM wrappers
__global__ __launch_bounds__(256) void kvproj_kernel(Ptr7 feats, const float* __restrict__ awk,
                                                     const float* __restrict__ abk,
                                                     const float* __restrict__ awv,
                                                     const float* __restrict__ abv,
                                                     float* __restrict__ ktab,
                                                     float* __restrict__ vtab) {
    __shared__ __align__(16) char smem[SMEM_BYTES];
    int v = blockIdx.z, ct = blockIdx.y, rt = blockIdx.x;
    bool isv = ct >= 2;
    int c2 = ct & 1;
    const float* A = feats.p[v] + (size_t)rt * 64 * CH;
    const float* W = (isv ? awv : awk) + (size_t)v * CH * CH + c2 * 64;
    const float* bias = (isv ? abv : abk) + v * CH + c2 * 64;
    float* Out = (isv ? vtab : ktab) + (size_t)v * (BATCH * NPTS) * CH + (size_t)rt * 64 * CH + c2 * 64;
    gemm_tile64<CH, false>(smem, A, CH, nullptr, W, CH, bias, Out, CH);
}

__global__ __launch_bounds__(256) void qproj_kernel(Ptr7 feats, const float* __restrict__ awq,
                                                    const float* __restrict__ abq,
                                                    const int* __restrict__ gatherC,
                                                    float* __restrict__ qtab) {
    __shared__ __align__(16) char smem[SMEM_BYTES];
    int v = blockIdx.z, ct = blockIdx.y, rt = blockIdx.x;
    gemm_tile64<CH, false>(smem, feats.p[v], CH, gatherC + rt * 64,
                           awq + (size_t)v * CH * CH + ct * 64, CH,
                           abq + v * CH + ct * 64,
                           qtab + ((size_t)v * (BATCH * NCEN) + rt * 64) * CH + ct * 64, CH);
}

__global__ __launch_bounds__(256) void mlp1_kernel(const float* __restrict__ otab,
                                                   const float* __restrict__ mw1,
                                                   const float* __restrict__ mb1,
                                                   float* __restrict__ htab) {
    __shared__ __align__(16) char smem[SMEM_BYTES];
    int v = blockIdx.z, ct = blockIdx.y, rt = blockIdx.x;
    gemm_tile64<CH, true>(smem, otab + ((size_t)v * (BATCH * NCEN) + rt * 64) * CH, CH, nullptr,
                          mw1 + (size_t)v * CH * CHO + ct * 64, CHO,
                          mb1 + v * CHO + ct * 64,
                          htab + ((size_t)v * (BATCH * NCEN) + rt * 64) * CHO + ct * 64, CHO);
}

__global__ __launch_bounds__(256) void mlp2_kernel(const float* __restrict__ htab,
                                                   const float* __restrict__ mw2,
                                                   const float* __restrict__ mb2,
                                                   float* __restrict__ out) {
    __shared__ __align__(16) char smem[SMEM_BYTES];
    int v = blockIdx.z, ct = blockIdx.y, rt = blockIdx.x;
    gemm_tile64<CHO, true>(smem, htab + ((size_t)v * (BATCH * NCEN) + rt * 64) * CHO, CHO, nullptr,
                           mw2 + (size_t)v * CHO * CHO + ct * 64, CHO,
                           mb2 + v * CHO + ct * 64,
                           out + ((size_t)v * (BATCH * NCEN) + rt * 64) * CHO + ct * 64, CHO);
}

// ---------------------------------------------------------------- attention
__global__ __launch_bounds__(256) void attn_kernel(const float* __restrict__ qtab,
                                                   const float* __restrict__ ktab,
                                                   const float* __restrict__ vtab,
                                                   const int* __restrict__ idx_sel,
                                                   float* __restrict__ otab) {
    __shared__ float q_s[4][CH];
    __shared__ float attn_s[4][NNEI];
    __shared__ int jj_s[4][NNEI];
    int v = blockIdx.y;
    int t = threadIdx.x, w = t >> 6, lane = t & 63;
    int cg = blockIdx.x * 4 + w;
    int b = cg >> 9, s = cg & 511;
    const float* qr = qtab + ((size_t)v * (BATCH * NCEN) + cg) * CH;
    *(float2*)&q_s[w][lane * 2] = *(const float2*)(qr + lane * 2);
    if (lane < NNEI) jj_s[w][lane] = idx_sel[((size_t)(b * NCEN + s)) * NNEI + lane];
    __syncthreads();
    if (lane < NNEI) {
        int j = jj_s[w][lane];
        const float* kr = ktab + ((size_t)v * (BATCH * NPTS) + b * NPTS + j) * CH;
        float acc = 0.f;
#pragma unroll
        for (int c4 = 0; c4 < CH / 4; c4++) {
            float4 qv = *(const float4*)&q_s[w][c4 * 4];
            float4 kv = *(const float4*)(kr + c4 * 4);
            acc += qv.x * kv.x + qv.y * kv.y + qv.z * kv.z + qv.w * kv.w;
        }
        float sc = acc * 0.08838834764831845f;  // 1/sqrt(128)
        float m = sc;
#pragma unroll
        for (int off = 16; off > 0; off >>= 1) m = fmaxf(m, __shfl_xor(m, off, 32));
        float e = expf(sc - m);
        float sum = e;
#pragma unroll
        for (int off = 16; off > 0; off >>= 1) sum += __shfl_xor(sum, off, 32);
        attn_s[w][lane] = e / sum;
    }
    __syncthreads();
    float2 o = {0.f, 0.f};
    const float* vbase = vtab + ((size_t)v * (BATCH * NPTS) + b * NPTS) * CH;
    for (int tt = 0; tt < NNEI; tt++) {
        int j = jj_s[w][tt];
        float a = attn_s[w][tt];
        float2 vv = *(const float2*)(vbase + (size_t)j * CH + lane * 2);
        o.x += a * vv.x;
        o.y += a * vv.y;
    }
    *(float2*)(otab + ((size_t)v * (BATCH * NCEN) + cg) * CH + lane * 2) = o;
}

// ---------------------------------------------------------------- launch
extern "C" void kernel_launch(void* const* d_in, const int* in_sizes, int n_in,
                              void* d_out, int out_size, void* d_ws, size_t ws_size,
                              hipStream_t stream) {
    (void)in_sizes; (void)n_in; (void)out_size;
    Ptr7 feats;
    for (int i = 0; i < 7; i++) feats.p[i] = (const float*)d_in[i];
    const float* awq = (const float*)d_in[7];
    const float* abq = (const float*)d_in[8];
    const float* awk = (const float*)d_in[9];
    const float* abk = (const float*)d_in[10];
    const float* awv = (const float*)d_in[11];
    const float* abv = (const float*)d_in[12];
    const float* mw1 = (const float*)d_in[13];
    const float* mb1 = (const float*)d_in[14];
    const float* mw2 = (const float*)d_in[15];
    const float* mb2 = (const float*)d_in[16];
    const float* xyz = feats.p[0];

    char* ws = (char*)d_ws;
    size_t SZ_D = (size_t)BATCH * NPTS * NPTS * 4;       // 134 MB
    float* D = (float*)ws;
    float* ktab = (float*)ws;                            // overlays D (dead after reach)
    float* vtab = (float*)(ws + (size_t)7 * BATCH * NPTS * CH * 4);
    size_t off = SZ_D;
    float* xx = (float*)(ws + off); off += (size_t)BATCH * NPTS * 4;
    unsigned* adjb = (unsigned*)(ws + off); off += (size_t)BATCH * NPTS * NW * 4;
    int* fpsidx = (int*)(ws + off); off += (size_t)BATCH * NCEN * 4;
    int* idxsel = (int*)(ws + off); off += (size_t)BATCH * NCEN * NNEI * 4;
    int* gatherC = (int*)(ws + off); off += (size_t)BATCH * NCEN * 4;
    float* qtab = (float*)(ws + off); off += (size_t)7 * BATCH * NCEN * CH * 4;
    float* otab = (float*)(ws + off); off += (size_t)7 * BATCH * NCEN * CH * 4;
    float* htab = (float*)(ws + off); off += (size_t)7 * BATCH * NCEN * CHO * 4;
    if (ws_size < off) return;

    xx_kernel<<<dim3((BATCH * NPTS + 255) / 256), dim3(256), 0, stream>>>(xyz, xx);
    dmat_kernel<<<dim3(NPTS / 64, NPTS / 64, BATCH), dim3(256), 0, stream>>>(xyz, xx, D);
    fused_front_kernel<<<dim3(BATCH + BATCH * NPTS), dim3(256), 0, stream>>>(D, adjb, fpsidx);
    make_gather<<<dim3((BATCH * NCEN + 255) / 256), dim3(256), 0, stream>>>(fpsidx, gatherC);
    reach_top32_kernel<<<dim3(NCEN, BATCH), dim3(256), 0, stream>>>(adjb, D, fpsidx, idxsel);
    // D dead: ktab/vtab overlay it
    kvproj_kernel<<<dim3(BATCH * NPTS / 64, 4, 7), dim3(256), 0, stream>>>(feats, awk, abk, awv, abv, ktab, vtab);
    qproj_kernel<<<dim3(BATCH * NCEN / 64, 2, 7), dim3(256), 0, stream>>>(feats, awq, abq, gatherC, qtab);
    attn_kernel<<<dim3(BATCH * NCEN / 4, 7), dim3(256), 0, stream>>>(qtab, ktab, vtab, idxsel, otab);
    mlp1_kernel<<<dim3(BATCH * NCEN / 64, 4, 7), dim3(256), 0, stream>>>(otab, mw1, mb1, htab);
    mlp2_kernel<<<dim3(BATCH * NCEN / 64, 4, 7), dim3(256), 0, stream>>>(htab, mw2, mb2, (float*)d_out);
}

// Round 17
// 1211.540 us; speedup vs baseline: 2.5953x; 2.5953x over previous
//
#include <hip/hip_runtime.h>
#include <hip/hip_bf16.h>
#include <math.h>

// Problem constants
constexpr int BATCH = 8;
constexpr int NPTS  = 2048;
constexpr int CH    = 128;
constexpr int CHO   = 256;
constexpr int NCEN  = 512;
constexpr int NNEI  = 32;   // n_near
constexpr int NTOP  = 11;   // n_stepk + 1
constexpr int NW    = 64;   // bitset words per row (2048/32)
constexpr int SMEM_BYTES = 17408;

struct Ptr7 { const float* p[7]; };

// ---------------------------------------------------------------- xx = sum(x^2)
__global__ __launch_bounds__(256) void xx_kernel(const float* __restrict__ x,
                                                 float* __restrict__ xx) {
    int p = blockIdx.x * 256 + threadIdx.x;
    if (p >= BATCH * NPTS) return;
    const float4* xr = (const float4*)(x + (size_t)p * CH);
    float s = 0.f;
#pragma unroll
    for (int i = 0; i < CH / 4; i++) {
        float4 v = xr[i];
        s += v.x * v.x + v.y * v.y + v.z * v.z + v.w * v.w;
    }
    xx[p] = s;
}

// ---------------------------------------------------------------- D (symmetric: jt>=it tiles, mirrored; bitwise-faithful)
__global__ __launch_bounds__(256) void dmat_kernel(const float* __restrict__ x,
                                                   const float* __restrict__ xx,
                                                   float* __restrict__ D) {
    __shared__ __align__(16) char smem[SMEM_BYTES];
    int it = blockIdx.y, jt = blockIdx.x;
    if (jt < it) return;
    float (*As)[68] = (float(*)[68])smem;
    float (*Bs)[68] = (float(*)[68])(smem + 32 * 68 * 4);
    int bz = blockIdx.z;
    int i0 = it * 64, j0 = jt * 64;
    const float* X = x + (size_t)bz * NPTS * CH;
    int t = threadIdx.x, tx = t & 15, ty = t >> 4;
    int lr = t >> 3, lc = (t & 7) * 4;
    const float* ai0 = X + (size_t)(i0 + lr) * CH;
    const float* ai1 = X + (size_t)(i0 + lr + 32) * CH;
    const float* bj0 = X + (size_t)(j0 + lr) * CH;
    const float* bj1 = X + (size_t)(j0 + lr + 32) * CH;
    float acc[4][4] = {};
    for (int kc = 0; kc < CH; kc += 32) {
        float4 a0 = *(const float4*)(ai0 + kc + lc);
        float4 a1 = *(const float4*)(ai1 + kc + lc);
        float4 b0 = *(const float4*)(bj0 + kc + lc);
        float4 b1 = *(const float4*)(bj1 + kc + lc);
        __syncthreads();
        As[lc + 0][lr] = a0.x; As[lc + 1][lr] = a0.y; As[lc + 2][lr] = a0.z; As[lc + 3][lr] = a0.w;
        As[lc + 0][lr + 32] = a1.x; As[lc + 1][lr + 32] = a1.y; As[lc + 2][lr + 32] = a1.z; As[lc + 3][lr + 32] = a1.w;
        Bs[lc + 0][lr] = b0.x; Bs[lc + 1][lr] = b0.y; Bs[lc + 2][lr] = b0.z; Bs[lc + 3][lr] = b0.w;
        Bs[lc + 0][lr + 32] = b1.x; Bs[lc + 1][lr + 32] = b1.y; Bs[lc + 2][lr + 32] = b1.z; Bs[lc + 3][lr + 32] = b1.w;
        __syncthreads();
#pragma unroll
        for (int kk = 0; kk < 32; kk++) {
            float4 av = *(const float4*)&As[kk][ty * 4];
            float4 bv = *(const float4*)&Bs[kk][tx * 4];
            float a[4] = {av.x, av.y, av.z, av.w};
            float b[4] = {bv.x, bv.y, bv.z, bv.w};
#pragma unroll
            for (int i = 0; i < 4; i++)
#pragma unroll
                for (int j = 0; j < 4; j++) acc[i][j] += a[i] * b[j];
        }
    }
    const float* xxb = xx + bz * NPTS;
    float xi[4], xj[4];
#pragma unroll
    for (int i = 0; i < 4; i++) xi[i] = xxb[i0 + ty * 4 + i];
#pragma unroll
    for (int j = 0; j < 4; j++) xj[j] = xxb[j0 + tx * 4 + j];
    float ov[4][4];
#pragma unroll
    for (int i = 0; i < 4; i++)
#pragma unroll
        for (int j = 0; j < 4; j++) ov[i][j] = xi[i] + xj[j] - 2.f * acc[i][j];
#pragma unroll
    for (int i = 0; i < 4; i++) {
        float4 o = {ov[i][0], ov[i][1], ov[i][2], ov[i][3]};
        *(float4*)(D + ((size_t)bz * NPTS + i0 + ty * 4 + i) * NPTS + j0 + tx * 4) = o;
    }
    if (jt > it) {
        __syncthreads();
        float (*T)[65] = (float(*)[65])smem;
#pragma unroll
        for (int i = 0; i < 4; i++)
#pragma unroll
            for (int j = 0; j < 4; j++) T[ty * 4 + i][tx * 4 + j] = ov[i][j];
        __syncthreads();
#pragma unroll
        for (int i = 0; i < 4; i++) {
            float4 o;
            o.x = T[tx * 4 + 0][ty * 4 + i];
            o.y = T[tx * 4 + 1][ty * 4 + i];
            o.z = T[tx * 4 + 2][ty * 4 + i];
            o.w = T[tx * 4 + 3][ty * 4 + i];
            *(float4*)(D + ((size_t)bz * NPTS + j0 + ty * 4 + i) * NPTS + i0 + tx * 4) = o;
        }
    }
}

// ---------------------------------------------------------------- fused front: fps (blocks 0..7) + top-11 (blocks 8..)
__global__ __launch_bounds__(256) void fused_front_kernel(const float* __restrict__ D,
                                                          unsigned int* __restrict__ adj,
                                                          int* __restrict__ fps_idx) {
    __shared__ __align__(16) char smem[SMEM_BYTES];
    if (blockIdx.x < BATCH) {
        // ---------------- FPS: one wave, registers, 4-chain ILP reduce ----------------
        int lane = threadIdx.x;
        if (lane >= 64) return;
        int b = blockIdx.x;
        float mind[32];
#pragma unroll
        for (int r = 0; r < 32; r++) mind[r] = INFINITY;
        int prev = 0;
        if (lane == 0) fps_idx[b * NCEN] = 0;
        const float* Db = D + (size_t)b * NPTS * NPTS;
        for (int s = 1; s < NCEN; s++) {
            const float4* rowp = (const float4*)(Db + (size_t)prev * NPTS);
            // 4 independent (value,index) chains over k-pairs; ascending j within chain
            float cv0 = -INFINITY, cv1 = -INFINITY, cv2 = -INFINITY, cv3 = -INFINITY;
            int cj0 = NPTS, cj1 = NPTS, cj2 = NPTS, cj3 = NPTS;
#pragma unroll
            for (int k = 0; k < 8; k++) {
                float4 g = rowp[lane + 64 * k];
                int j0 = 4 * (lane + 64 * k);
                float m0 = fminf(mind[4 * k + 0], g.x); mind[4 * k + 0] = m0;
                float m1 = fminf(mind[4 * k + 1], g.y); mind[4 * k + 1] = m1;
                float m2 = fminf(mind[4 * k + 2], g.z); mind[4 * k + 2] = m2;
                float m3 = fminf(mind[4 * k + 3], g.w); mind[4 * k + 3] = m3;
                // chain c = k>>1 (ascending j within chain; strict > keeps lowest idx)
                if ((k >> 1) == 0) {
                    if (m0 > cv0) { cv0 = m0; cj0 = j0 + 0; }
                    if (m1 > cv0) { cv0 = m1; cj0 = j0 + 1; }
                    if (m2 > cv0) { cv0 = m2; cj0 = j0 + 2; }
                    if (m3 > cv0) { cv0 = m3; cj0 = j0 + 3; }
                } else if ((k >> 1) == 1) {
                    if (m0 > cv1) { cv1 = m0; cj1 = j0 + 0; }
                    if (m1 > cv1) { cv1 = m1; cj1 = j0 + 1; }
                    if (m2 > cv1) { cv1 = m2; cj1 = j0 + 2; }
                    if (m3 > cv1) { cv1 = m3; cj1 = j0 + 3; }
                } else if ((k >> 1) == 2) {
                    if (m0 > cv2) { cv2 = m0; cj2 = j0 + 0; }
                    if (m1 > cv2) { cv2 = m1; cj2 = j0 + 1; }
                    if (m2 > cv2) { cv2 = m2; cj2 = j0 + 2; }
                    if (m3 > cv2) { cv2 = m3; cj2 = j0 + 3; }
                } else {
                    if (m0 > cv3) { cv3 = m0; cj3 = j0 + 0; }
                    if (m1 > cv3) { cv3 = m1; cj3 = j0 + 1; }
                    if (m2 > cv3) { cv3 = m2; cj3 = j0 + 2; }
                    if (m3 > cv3) { cv3 = m3; cj3 = j0 + 3; }
                }
            }
            // merge 4 chains (explicit index tie-break; associative)
            if (cv1 > cv0 || (cv1 == cv0 && cj1 < cj0)) { cv0 = cv1; cj0 = cj1; }
            if (cv3 > cv2 || (cv3 == cv2 && cj3 < cj2)) { cv2 = cv3; cj2 = cj3; }
            float bv = cv0; int bj = cj0;
            if (cv2 > bv || (cv2 == bv && cj2 < bj)) { bv = cv2; bj = cj2; }
            // 64-lane butterfly argmax, tie -> lowest index
#pragma unroll
            for (int off = 32; off > 0; off >>= 1) {
                float ovv = __shfl_xor(bv, off);
                int oj = __shfl_xor(bj, off);
                if (ovv > bv || (ovv == bv && oj < bj)) { bv = ovv; bj = oj; }
            }
            if (lane == 0) fps_idx[b * NCEN + s] = bj;
            prev = bj;   // all lanes agree
        }
        return;
    }
    // ---------------- top-11 ----------------
    float* row = (float*)smem;
    float* rv = row + NPTS;
    int* ri = (int*)(rv + 256);
    int* picks = ri + 256;
    int rid = blockIdx.x - BATCH;
    const float* Dr = D + (size_t)rid * NPTS;
    int t = threadIdx.x;
    float4* rp = (float4*)row;
    rp[t] = ((const float4*)Dr)[t];
    rp[t + 256] = ((const float4*)Dr)[t + 256];
    __syncthreads();
    for (int it = 0; it < NTOP; it++) {
        float bv = row[t];
        int bi = t;
#pragma unroll
        for (int k = 1; k < 8; k++) {
            int j = t + (k << 8);
            float v = row[j];
            if (v < bv) { bv = v; bi = j; }
        }
        rv[t] = bv; ri[t] = bi;
        __syncthreads();
        for (int off = 128; off > 0; off >>= 1) {
            if (t < off) {
                float ovv = rv[t + off]; int oi = ri[t + off];
                if (ovv < rv[t] || (ovv == rv[t] && oi < ri[t])) { rv[t] = ovv; ri[t] = oi; }
            }
            __syncthreads();
        }
        if (t == 0) { picks[it] = ri[0]; row[ri[0]] = INFINITY; }
        __syncthreads();
    }
    if (t < NW) {
        unsigned w = 0;
#pragma unroll
        for (int p = 0; p < NTOP; p++) {
            int j = picks[p];
            if ((j >> 5) == t) w |= 1u << (j & 31);
        }
        adj[(size_t)rid * NW + t] = w;
    }
}

// ---------------------------------------------------------------- gather indices
__global__ void make_gather(const int* __restrict__ fps_idx, int* __restrict__ gatherC) {
    int r = blockIdx.x * 256 + threadIdx.x;
    if (r >= BATCH * NCEN) return;
    int b = r >> 9, s = r & 511;
    gatherC[r] = b * NPTS + fps_idx[b * NCEN + s];
}

// ---------------------------------------------------------------- 2-hop reach + top-32 on fp32 D
__global__ __launch_bounds__(256) void reach_top32_kernel(const unsigned int* __restrict__ adj,
                                                          const float* __restrict__ D,
                                                          const int* __restrict__ fps_idx,
                                                          int* __restrict__ idx_sel) {
    __shared__ unsigned adjw[NW], R1[NW], R2[NW];
    __shared__ int lst[NPTS];
    __shared__ float dst[NPTS];
    __shared__ int cnt;
    __shared__ float rv[256];
    __shared__ int rj[256], rp[256];
    __shared__ int sel[NNEI];
    int s = blockIdx.x, b = blockIdx.y, t = threadIdx.x;
    int i = fps_idx[b * NCEN + s];
    const unsigned* arow = adj + ((size_t)(b * NPTS + i)) * NW;
    if (t < NW) { adjw[t] = arow[t]; R1[t] = arow[t]; }
    if (t == 0) cnt = 0;
    __syncthreads();
    if (t < NW) {
        unsigned w = adjw[t];
        while (w) { int bb = __ffs(w) - 1; w &= w - 1; int p = atomicAdd(&cnt, 1); lst[p] = t * 32 + bb; }
    }
    __syncthreads();
    int n1 = cnt;
    {
        int g = t >> 6, lane = t & 63;
        for (int p = g; p < n1; p += 4) {
            unsigned aw = adj[((size_t)(b * NPTS + lst[p])) * NW + lane];
            atomicOr(&R1[lane], aw);
        }
    }
    __syncthreads();
    if (t == 0) cnt = 0;
    __syncthreads();
    if (t < NW) {
        unsigned w = R1[t];
        while (w) { int bb = __ffs(w) - 1; w &= w - 1; int p = atomicAdd(&cnt, 1); lst[p] = t * 32 + bb; }
        R2[t] = adjw[t];
    }
    __syncthreads();
    int n2 = cnt;
    {
        int g = t >> 6, lane = t & 63;
        for (int p = g; p < n2; p += 4) {
            unsigned aw = adj[((size_t)(b * NPTS + lst[p])) * NW + lane];
            atomicOr(&R2[lane], aw);
        }
    }
    __syncthreads();
    if (t == 0) cnt = 0;
    __syncthreads();
    const float* Dr = D + (size_t)(b * NPTS + i) * NPTS;
    if (t < NW) {
        unsigned w = R2[t];
        while (w) {
            int bb = __ffs(w) - 1; w &= w - 1;
            int j = t * 32 + bb;
            int p = atomicAdd(&cnt, 1);
            lst[p] = j; dst[p] = Dr[j];
        }
    }
    __syncthreads();
    int L = cnt;
    int nsel = L < NNEI ? L : NNEI;
    for (int r = 0; r < nsel; r++) {
        float bv = INFINITY; int bj = 0x7fffffff, bp = -1;
        for (int p = t; p < L; p += 256) {
            float v = dst[p]; int j = lst[p];
            if (v < bv || (v == bv && j < bj)) { bv = v; bj = j; bp = p; }
        }
        rv[t] = bv; rj[t] = bj; rp[t] = bp;
        __syncthreads();
        for (int off = 128; off > 0; off >>= 1) {
            if (t < off) {
                if (rv[t + off] < rv[t] || (rv[t + off] == rv[t] && rj[t + off] < rj[t])) {
                    rv[t] = rv[t + off]; rj[t] = rj[t + off]; rp[t] = rp[t + off];
                }
            }
            __syncthreads();
        }
        if (t == 0) { sel[r] = rj[0]; dst[rp[0]] = INFINITY; }
        __syncthreads();
    }
    if (t == 0 && nsel < NNEI) {
        int r = nsel;
        for (int j = 0; j < NPTS && r < NNEI; j++)
            if (!((R2[j >> 5] >> (j & 31)) & 1)) sel[r++] = j;
    }
    __syncthreads();
    if (t < NNEI) idx_sel[((size_t)(b * NCEN + s)) * NNEI + t] = sel[t];
}

// ---------------------------------------------------------------- 64x64 fp32 GEMM tile (smem arena)
template <int KSIZE, bool RELU>
__device__ __forceinline__ void gemm_tile64(char* smem,
                                            const float* __restrict__ A, int lda,
                                            const int* __restrict__ gather,
                                            const float* __restrict__ W, int ldw,
                                            const float* __restrict__ bias,
                                            float* __restrict__ Out, int ldo) {
    float (*As)[68] = (float(*)[68])smem;
    float (*Ws)[68] = (float(*)[68])(smem + 32 * 68 * 4);
    int t = threadIdx.x;
    int tx = t & 15, ty = t >> 4;
    int lr = t >> 3, lc = (t & 7) * 4;
    const float* ar0 = A + (size_t)(gather ? gather[lr] : lr) * lda;
    const float* ar1 = A + (size_t)(gather ? gather[lr + 32] : lr + 32) * lda;
    float acc[4][4] = {};
    for (int kc = 0; kc < KSIZE; kc += 32) {
        float4 a0 = *(const float4*)(ar0 + kc + lc);
        float4 a1 = *(const float4*)(ar1 + kc + lc);
        float4 w0 = *(const float4*)(W + (size_t)(kc + lr) * ldw + lc);
        float4 w1 = *(const float4*)(W + (size_t)(kc + lr) * ldw + lc + 32);
        __syncthreads();
        As[lc + 0][lr] = a0.x; As[lc + 1][lr] = a0.y; As[lc + 2][lr] = a0.z; As[lc + 3][lr] = a0.w;
        As[lc + 0][lr + 32] = a1.x; As[lc + 1][lr + 32] = a1.y; As[lc + 2][lr + 32] = a1.z; As[lc + 3][lr + 32] = a1.w;
        *(float4*)&Ws[lr][lc] = w0;
        *(float4*)&Ws[lr][lc + 32] = w1;
        __syncthreads();
#pragma unroll
        for (int kk = 0; kk < 32; kk++) {
            float4 av = *(const float4*)&As[kk][ty * 4];
            float4 wv = *(const float4*)&Ws[kk][tx * 4];
            float a[4] = {av.x, av.y, av.z, av.w};
            float w[4] = {wv.x, wv.y, wv.z, wv.w};
#pragma unroll
            for (int i = 0; i < 4; i++)
#pragma unroll
                for (int j = 0; j < 4; j++) acc[i][j] += a[i] * w[j];
        }
    }
#pragma unroll
    for (int i = 0; i < 4; i++) {
        int r = ty * 4 + i;
        float4 o;
        o.x = acc[i][0] + bias[tx * 4 + 0];
        o.y = acc[i][1] + bias[tx * 4 + 1];
        o.z = acc[i][2] + bias[tx * 4 + 2];
        o.w = acc[i][3] + bias[tx * 4 + 3];
        if (RELU) {
            o.x = fmaxf(o.x, 0.f); o.y = fmaxf(o.y, 0.f);
            o.z = fmaxf(o.z, 0.f); o.w = fmaxf(o.w, 0.f);
        }
        *(float4*)(Out + (size_t)r * ldo + tx * 4) = o;
    }
}

// ---------------------------------------------------------------- GEMM wrappers
__global__ __launch_bounds__(256) void kvproj_kernel(Ptr7 feats, const float* __restrict__ awk,
                                                     const float* __restrict__ abk,
                                                     const float* __restrict__ awv,
                                                     const float* __restrict__ abv,
                                                     float* __restrict__ ktab,
                                                     float* __restrict__ vtab) {
    __shared__ __align__(16) char smem[SMEM_BYTES];
    int v = blockIdx.z, ct = blockIdx.y, rt = blockIdx.x;
    bool isv = ct >= 2;
    int c2 = ct & 1;
    const float* A = feats.p[v] + (size_t)rt * 64 * CH;
    const float* W = (isv ? awv : awk) + (size_t)v * CH * CH + c2 * 64;
    const float* bias = (isv ? abv : abk) + v * CH + c2 * 64;
    float* Out = (isv ? vtab : ktab) + (size_t)v * (BATCH * NPTS) * CH + (size_t)rt * 64 * CH + c2 * 64;
    gemm_tile64<CH, false>(smem, A, CH, nullptr, W, CH, bias, Out, CH);
}

__global__ __launch_bounds__(256) void qproj_kernel(Ptr7 feats, const float* __restrict__ awq,
                                                    const float* __restrict__ abq,
                                                    const int* __restrict__ gatherC,
                                                    float* __restrict__ qtab) {
    __shared__ __align__(16) char smem[SMEM_BYTES];
    int v = blockIdx.z, ct = blockIdx.y, rt = blockIdx.x;
    gemm_tile64<CH, false>(smem, feats.p[v], CH, gatherC + rt * 64,
                           awq + (size_t)v * CH * CH + ct * 64, CH,
                           abq + v * CH + ct * 64,
                           qtab + ((size_t)v * (BATCH * NCEN) + rt * 64) * CH + ct * 64, CH);
}

__global__ __launch_bounds__(256) void mlp1_kernel(const float* __restrict__ otab,
                                                   const float* __restrict__ mw1,
                                                   const float* __restrict__ mb1,
                                                   float* __restrict__ htab) {
    __shared__ __align__(16) char smem[SMEM_BYTES];
    int v = blockIdx.z, ct = blockIdx.y, rt = blockIdx.x;
    gemm_tile64<CH, true>(smem, otab + ((size_t)v * (BATCH * NCEN) + rt * 64) * CH, CH, nullptr,
                          mw1 + (size_t)v * CH * CHO + ct * 64, CHO,
                          mb1 + v * CHO + ct * 64,
                          htab + ((size_t)v * (BATCH * NCEN) + rt * 64) * CHO + ct * 64, CHO);
}

__global__ __launch_bounds__(256) void mlp2_kernel(const float* __restrict__ htab,
                                                   const float* __restrict__ mw2,
                                                   const float* __restrict__ mb2,
                                                   float* __restrict__ out) {
    __shared__ __align__(16) char smem[SMEM_BYTES];
    int v = blockIdx.z, ct = blockIdx.y, rt = blockIdx.x;
    gemm_tile64<CHO, true>(smem, htab + ((size_t)v * (BATCH * NCEN) + rt * 64) * CHO, CHO, nullptr,
                           mw2 + (size_t)v * CHO * CHO + ct * 64, CHO,
                           mb2 + v * CHO + ct * 64,
                           out + ((size_t)v * (BATCH * NCEN) + rt * 64) * CHO + ct * 64, CHO);
}

// ---------------------------------------------------------------- attention
__global__ __launch_bounds__(256) void attn_kernel(const float* __restrict__ qtab,
                                                   const float* __restrict__ ktab,
                                                   const float* __restrict__ vtab,
                                                   const int* __restrict__ idx_sel,
                                                   float* __restrict__ otab) {
    __shared__ float q_s[4][CH];
    __shared__ float attn_s[4][NNEI];
    __shared__ int jj_s[4][NNEI];
    int v = blockIdx.y;
    int t = threadIdx.x, w = t >> 6, lane = t & 63;
    int cg = blockIdx.x * 4 + w;
    int b = cg >> 9, s = cg & 511;
    const float* qr = qtab + ((size_t)v * (BATCH * NCEN) + cg) * CH;
    *(float2*)&q_s[w][lane * 2] = *(const float2*)(qr + lane * 2);
    if (lane < NNEI) jj_s[w][lane] = idx_sel[((size_t)(b * NCEN + s)) * NNEI + lane];
    __syncthreads();
    if (lane < NNEI) {
        int j = jj_s[w][lane];
        const float* kr = ktab + ((size_t)v * (BATCH * NPTS) + b * NPTS + j) * CH;
        float acc = 0.f;
#pragma unroll
        for (int c4 = 0; c4 < CH / 4; c4++) {
            float4 qv = *(const float4*)&q_s[w][c4 * 4];
            float4 kv = *(const float4*)(kr + c4 * 4);
            acc += qv.x * kv.x + qv.y * kv.y + qv.z * kv.z + qv.w * kv.w;
        }
        float sc = acc * 0.08838834764831845f;  // 1/sqrt(128)
        float m = sc;
#pragma unroll
        for (int off = 16; off > 0; off >>= 1) m = fmaxf(m, __shfl_xor(m, off, 32));
        float e = expf(sc - m);
        float sum = e;
#pragma unroll
        for (int off = 16; off > 0; off >>= 1) sum += __shfl_xor(sum, off, 32);
        attn_s[w][lane] = e / sum;
    }
    __syncthreads();
    float2 o = {0.f, 0.f};
    const float* vbase = vtab + ((size_t)v * (BATCH * NPTS) + b * NPTS) * CH;
    for (int tt = 0; tt < NNEI; tt++) {
        int j = jj_s[w][tt];
        float a = attn_s[w][tt];
        float2 vv = *(const float2*)(vbase + (size_t)j * CH + lane * 2);
        o.x += a * vv.x;
        o.y += a * vv.y;
    }
    *(float2*)(otab + ((size_t)v * (BATCH * NCEN) + cg) * CH + lane * 2) = o;
}

// ---------------------------------------------------------------- launch
extern "C" void kernel_launch(void* const* d_in, const int* in_sizes, int n_in,
                              void* d_out, int out_size, void* d_ws, size_t ws_size,
                              hipStream_t stream) {
    (void)in_sizes; (void)n_in; (void)out_size;
    Ptr7 feats;
    for (int i = 0; i < 7; i++) feats.p[i] = (const float*)d_in[i];
    const float* awq = (const float*)d_in[7];
    const float* abq = (const float*)d_in[8];
    const float* awk = (const float*)d_in[9];
    const float* abk = (const float*)d_in[10];
    const float* awv = (const float*)d_in[11];
    const float* abv = (const float*)d_in[12];
    const float* mw1 = (const float*)d_in[13];
    const float* mb1 = (const float*)d_in[14];
    const float* mw2 = (const float*)d_in[15];
    const float* mb2 = (const float*)d_in[16];
    const float* xyz = feats.p[0];

    char* ws = (char*)d_ws;
    size_t SZ_D = (size_t)BATCH * NPTS * NPTS * 4;       // 134 MB
    float* D = (float*)ws;
    float* ktab = (float*)ws;                            // overlays D (dead after reach)
    float* vtab = (float*)(ws + (size_t)7 * BATCH * NPTS * CH * 4);
    size_t off = SZ_D;
    float* xx = (float*)(ws + off); off += (size_t)BATCH * NPTS * 4;
    unsigned* adjb = (unsigned*)(ws + off); off += (size_t)BATCH * NPTS * NW * 4;
    int* fpsidx = (int*)(ws + off); off += (size_t)BATCH * NCEN * 4;
    int* idxsel = (int*)(ws + off); off += (size_t)BATCH * NCEN * NNEI * 4;
    int* gatherC = (int*)(ws + off); off += (size_t)BATCH * NCEN * 4;
    float* qtab = (float*)(ws + off); off += (size_t)7 * BATCH * NCEN * CH * 4;
    float* otab = (float*)(ws + off); off += (size_t)7 * BATCH * NCEN * CH * 4;
    float* htab = (float*)(ws + off); off += (size_t)7 * BATCH * NCEN * CHO * 4;
    if (ws_size < off) return;

    xx_kernel<<<dim3((BATCH * NPTS + 255) / 256), dim3(256), 0, stream>>>(xyz, xx);
    dmat_kernel<<<dim3(NPTS / 64, NPTS / 64, BATCH), dim3(256), 0, stream>>>(xyz, xx, D);
    fused_front_kernel<<<dim3(BATCH + BATCH * NPTS), dim3(256), 0, stream>>>(D, adjb, fpsidx);
    make_gather<<<dim3((BATCH * NCEN + 255) / 256), dim3(256), 0, stream>>>(fpsidx, gatherC);
    reach_top32_kernel<<<dim3(NCEN, BATCH), dim3(256), 0, stream>>>(adjb, D, fpsidx, idxsel);
    // D dead: ktab/vtab overlay it
    kvproj_kernel<<<dim3(BATCH * NPTS / 64, 4, 7), dim3(256), 0, stream>>>(feats, awk, abk, awv, abv, ktab, vtab);
    qproj_kernel<<<dim3(BATCH * NCEN / 64, 2, 7), dim3(256), 0, stream>>>(feats, awq, abq, gatherC, qtab);
    attn_kernel<<<dim3(BATCH * NCEN / 4, 7), dim3(256), 0, stream>>>(qtab, ktab, vtab, idxsel, otab);
    mlp1_kernel<<<dim3(BATCH * NCEN / 64, 4, 7), dim3(256), 0, stream>>>(otab, mw1, mb1, htab);
    mlp2_kernel<<<dim3(BATCH * NCEN / 64, 4, 7), dim3(256), 0, stream>>>(htab, mw2, mb2, (float*)d_out);
}

// Round 18
// 1169.647 us; speedup vs baseline: 2.6882x; 1.0358x over previous
//
#include <hip/hip_runtime.h>
#include <hip/hip_bf16.h>
#include <math.h>

// Problem constants
constexpr int BATCH = 8;
constexpr int NPTS  = 2048;
constexpr int CH    = 128;
constexpr int CHO   = 256;
constexpr int NCEN  = 512;
constexpr int NNEI  = 32;   // n_near
constexpr int NTOP  = 11;   // n_stepk + 1
constexpr int NW    = 64;   // bitset words per row (2048/32)
constexpr int SMEM_BYTES = 17408;   // gemm/top11 arena
constexpr int SMEM_MID   = 20608;   // reach arena (superset of gemm arena)

struct Ptr7 { const float* p[7]; };

// ---------------------------------------------------------------- xx = sum(x^2)
__global__ __launch_bounds__(256) void xx_kernel(const float* __restrict__ x,
                                                 float* __restrict__ xx) {
    int p = blockIdx.x * 256 + threadIdx.x;
    if (p >= BATCH * NPTS) return;
    const float4* xr = (const float4*)(x + (size_t)p * CH);
    float s = 0.f;
#pragma unroll
    for (int i = 0; i < CH / 4; i++) {
        float4 v = xr[i];
        s += v.x * v.x + v.y * v.y + v.z * v.z + v.w * v.w;
    }
    xx[p] = s;
}

// ---------------------------------------------------------------- D (symmetric: jt>=it tiles, mirrored; bitwise-faithful)
__global__ __launch_bounds__(256) void dmat_kernel(const float* __restrict__ x,
                                                   const float* __restrict__ xx,
                                                   float* __restrict__ D) {
    __shared__ __align__(16) char smem[SMEM_BYTES];
    int it = blockIdx.y, jt = blockIdx.x;
    if (jt < it) return;
    float (*As)[68] = (float(*)[68])smem;
    float (*Bs)[68] = (float(*)[68])(smem + 32 * 68 * 4);
    int bz = blockIdx.z;
    int i0 = it * 64, j0 = jt * 64;
    const float* X = x + (size_t)bz * NPTS * CH;
    int t = threadIdx.x, tx = t & 15, ty = t >> 4;
    int lr = t >> 3, lc = (t & 7) * 4;
    const float* ai0 = X + (size_t)(i0 + lr) * CH;
    const float* ai1 = X + (size_t)(i0 + lr + 32) * CH;
    const float* bj0 = X + (size_t)(j0 + lr) * CH;
    const float* bj1 = X + (size_t)(j0 + lr + 32) * CH;
    float acc[4][4] = {};
    for (int kc = 0; kc < CH; kc += 32) {
        float4 a0 = *(const float4*)(ai0 + kc + lc);
        float4 a1 = *(const float4*)(ai1 + kc + lc);
        float4 b0 = *(const float4*)(bj0 + kc + lc);
        float4 b1 = *(const float4*)(bj1 + kc + lc);
        __syncthreads();
        As[lc + 0][lr] = a0.x; As[lc + 1][lr] = a0.y; As[lc + 2][lr] = a0.z; As[lc + 3][lr] = a0.w;
        As[lc + 0][lr + 32] = a1.x; As[lc + 1][lr + 32] = a1.y; As[lc + 2][lr + 32] = a1.z; As[lc + 3][lr + 32] = a1.w;
        Bs[lc + 0][lr] = b0.x; Bs[lc + 1][lr] = b0.y; Bs[lc + 2][lr] = b0.z; Bs[lc + 3][lr] = b0.w;
        Bs[lc + 0][lr + 32] = b1.x; Bs[lc + 1][lr + 32] = b1.y; Bs[lc + 2][lr + 32] = b1.z; Bs[lc + 3][lr + 32] = b1.w;
        __syncthreads();
#pragma unroll
        for (int kk = 0; kk < 32; kk++) {
            float4 av = *(const float4*)&As[kk][ty * 4];
            float4 bv = *(const float4*)&Bs[kk][tx * 4];
            float a[4] = {av.x, av.y, av.z, av.w};
            float b[4] = {bv.x, bv.y, bv.z, bv.w};
#pragma unroll
            for (int i = 0; i < 4; i++)
#pragma unroll
                for (int j = 0; j < 4; j++) acc[i][j] += a[i] * b[j];
        }
    }
    const float* xxb = xx + bz * NPTS;
    float xi[4], xj[4];
#pragma unroll
    for (int i = 0; i < 4; i++) xi[i] = xxb[i0 + ty * 4 + i];
#pragma unroll
    for (int j = 0; j < 4; j++) xj[j] = xxb[j0 + tx * 4 + j];
    float ov[4][4];
#pragma unroll
    for (int i = 0; i < 4; i++)
#pragma unroll
        for (int j = 0; j < 4; j++) ov[i][j] = xi[i] + xj[j] - 2.f * acc[i][j];
#pragma unroll
    for (int i = 0; i < 4; i++) {
        float4 o = {ov[i][0], ov[i][1], ov[i][2], ov[i][3]};
        *(float4*)(D + ((size_t)bz * NPTS + i0 + ty * 4 + i) * NPTS + j0 + tx * 4) = o;
    }
    if (jt > it) {
        __syncthreads();
        float (*T)[65] = (float(*)[65])smem;
#pragma unroll
        for (int i = 0; i < 4; i++)
#pragma unroll
            for (int j = 0; j < 4; j++) T[ty * 4 + i][tx * 4 + j] = ov[i][j];
        __syncthreads();
#pragma unroll
        for (int i = 0; i < 4; i++) {
            float4 o;
            o.x = T[tx * 4 + 0][ty * 4 + i];
            o.y = T[tx * 4 + 1][ty * 4 + i];
            o.z = T[tx * 4 + 2][ty * 4 + i];
            o.w = T[tx * 4 + 3][ty * 4 + i];
            *(float4*)(D + ((size_t)bz * NPTS + j0 + ty * 4 + i) * NPTS + i0 + tx * 4) = o;
        }
    }
}

// ---------------------------------------------------------------- fused front: fps (blocks 0..7) + top-11 (blocks 8..)
// fps: round-14 serial-chain register version (known-good 1.11 us/step).
__global__ __launch_bounds__(256) void fused_front_kernel(const float* __restrict__ D,
                                                          unsigned int* __restrict__ adj,
                                                          int* __restrict__ fps_idx) {
    __shared__ __align__(16) char smem[SMEM_BYTES];
    if (blockIdx.x < BATCH) {
        int lane = threadIdx.x;
        if (lane >= 64) return;
        int b = blockIdx.x;
        float mind[32];
#pragma unroll
        for (int r = 0; r < 32; r++) mind[r] = INFINITY;
        int prev = 0;
        if (lane == 0) fps_idx[b * NCEN] = 0;
        const float* Db = D + (size_t)b * NPTS * NPTS;
        for (int s = 1; s < NCEN; s++) {
            const float4* rowp = (const float4*)(Db + (size_t)prev * NPTS);
            float4 v0 = rowp[lane + 0 * 64];
            float4 v1 = rowp[lane + 1 * 64];
            float4 v2 = rowp[lane + 2 * 64];
            float4 v3 = rowp[lane + 3 * 64];
            float4 v4 = rowp[lane + 4 * 64];
            float4 v5 = rowp[lane + 5 * 64];
            float4 v6 = rowp[lane + 6 * 64];
            float4 v7 = rowp[lane + 7 * 64];
            float bv = -INFINITY; int bj = NPTS;
            float4 vv[8] = {v0, v1, v2, v3, v4, v5, v6, v7};
#pragma unroll
            for (int k = 0; k < 8; k++) {
                int j0 = 4 * (lane + 64 * k);
                float m0 = fminf(mind[4 * k + 0], vv[k].x); mind[4 * k + 0] = m0;
                float m1 = fminf(mind[4 * k + 1], vv[k].y); mind[4 * k + 1] = m1;
                float m2 = fminf(mind[4 * k + 2], vv[k].z); mind[4 * k + 2] = m2;
                float m3 = fminf(mind[4 * k + 3], vv[k].w); mind[4 * k + 3] = m3;
                // ascending j -> strict > keeps lowest index on ties
                if (m0 > bv) { bv = m0; bj = j0 + 0; }
                if (m1 > bv) { bv = m1; bj = j0 + 1; }
                if (m2 > bv) { bv = m2; bj = j0 + 2; }
                if (m3 > bv) { bv = m3; bj = j0 + 3; }
            }
#pragma unroll
            for (int off = 32; off > 0; off >>= 1) {
                float ov = __shfl_xor(bv, off);
                int oj = __shfl_xor(bj, off);
                if (ov > bv || (ov == bv && oj < bj)) { bv = ov; bj = oj; }
            }
            if (lane == 0) fps_idx[b * NCEN + s] = bj;
            prev = bj;   // all lanes agree
        }
        return;
    }
    // ---------------- top-11 ----------------
    float* row = (float*)smem;
    float* rv = row + NPTS;
    int* ri = (int*)(rv + 256);
    int* picks = ri + 256;
    int rid = blockIdx.x - BATCH;
    const float* Dr = D + (size_t)rid * NPTS;
    int t = threadIdx.x;
    float4* rp = (float4*)row;
    rp[t] = ((const float4*)Dr)[t];
    rp[t + 256] = ((const float4*)Dr)[t + 256];
    __syncthreads();
    for (int it = 0; it < NTOP; it++) {
        float bv = row[t];
        int bi = t;
#pragma unroll
        for (int k = 1; k < 8; k++) {
            int j = t + (k << 8);
            float v = row[j];
            if (v < bv) { bv = v; bi = j; }
        }
        rv[t] = bv; ri[t] = bi;
        __syncthreads();
        for (int off = 128; off > 0; off >>= 1) {
            if (t < off) {
                float ovv = rv[t + off]; int oi = ri[t + off];
                if (ovv < rv[t] || (ovv == rv[t] && oi < ri[t])) { rv[t] = ovv; ri[t] = oi; }
            }
            __syncthreads();
        }
        if (t == 0) { picks[it] = ri[0]; row[ri[0]] = INFINITY; }
        __syncthreads();
    }
    if (t < NW) {
        unsigned w = 0;
#pragma unroll
        for (int p = 0; p < NTOP; p++) {
            int j = picks[p];
            if ((j >> 5) == t) w |= 1u << (j & 31);
        }
        adj[(size_t)rid * NW + t] = w;
    }
}

// ---------------------------------------------------------------- gather indices
__global__ void make_gather(const int* __restrict__ fps_idx, int* __restrict__ gatherC) {
    int r = blockIdx.x * 256 + threadIdx.x;
    if (r >= BATCH * NCEN) return;
    int b = r >> 9, s = r & 511;
    gatherC[r] = b * NPTS + fps_idx[b * NCEN + s];
}

// ---------------------------------------------------------------- 64x64 fp32 GEMM tile (smem arena)
template <int KSIZE, bool RELU>
__device__ __forceinline__ void gemm_tile64(char* smem,
                                            const float* __restrict__ A, int lda,
                                            const int* __restrict__ gather,
                                            const float* __restrict__ W, int ldw,
                                            const float* __restrict__ bias,
                                            float* __restrict__ Out, int ldo) {
    float (*As)[68] = (float(*)[68])smem;
    float (*Ws)[68] = (float(*)[68])(smem + 32 * 68 * 4);
    int t = threadIdx.x;
    int tx = t & 15, ty = t >> 4;
    int lr = t >> 3, lc = (t & 7) * 4;
    const float* ar0 = A + (size_t)(gather ? gather[lr] : lr) * lda;
    const float* ar1 = A + (size_t)(gather ? gather[lr + 32] : lr + 32) * lda;
    float acc[4][4] = {};
    for (int kc = 0; kc < KSIZE; kc += 32) {
        float4 a0 = *(const float4*)(ar0 + kc + lc);
        float4 a1 = *(const float4*)(ar1 + kc + lc);
        float4 w0 = *(const float4*)(W + (size_t)(kc + lr) * ldw + lc);
        float4 w1 = *(const float4*)(W + (size_t)(kc + lr) * ldw + lc + 32);
        __syncthreads();
        As[lc + 0][lr] = a0.x; As[lc + 1][lr] = a0.y; As[lc + 2][lr] = a0.z; As[lc + 3][lr] = a0.w;
        As[lc + 0][lr + 32] = a1.x; As[lc + 1][lr + 32] = a1.y; As[lc + 2][lr + 32] = a1.z; As[lc + 3][lr + 32] = a1.w;
        *(float4*)&Ws[lr][lc] = w0;
        *(float4*)&Ws[lr][lc + 32] = w1;
        __syncthreads();
#pragma unroll
        for (int kk = 0; kk < 32; kk++) {
            float4 av = *(const float4*)&As[kk][ty * 4];
            float4 wv = *(const float4*)&Ws[kk][tx * 4];
            float a[4] = {av.x, av.y, av.z, av.w};
            float w[4] = {wv.x, wv.y, wv.z, wv.w};
#pragma unroll
            for (int i = 0; i < 4; i++)
#pragma unroll
                for (int j = 0; j < 4; j++) acc[i][j] += a[i] * w[j];
        }
    }
#pragma unroll
    for (int i = 0; i < 4; i++) {
        int r = ty * 4 + i;
        float4 o;
        o.x = acc[i][0] + bias[tx * 4 + 0];
        o.y = acc[i][1] + bias[tx * 4 + 1];
        o.z = acc[i][2] + bias[tx * 4 + 2];
        o.w = acc[i][3] + bias[tx * 4 + 3];
        if (RELU) {
            o.x = fmaxf(o.x, 0.f); o.y = fmaxf(o.y, 0.f);
            o.z = fmaxf(o.z, 0.f); o.w = fmaxf(o.w, 0.f);
        }
        *(float4*)(Out + (size_t)r * ldo + tx * 4) = o;
    }
}

// ---------------------------------------------------------------- fused mid: reach+top32 (blocks 0..4095) + qproj (blocks 4096..4991)
__global__ __launch_bounds__(256) void fused_mid_kernel(const unsigned int* __restrict__ adj,
                                                        const float* __restrict__ D,
                                                        const int* __restrict__ fps_idx,
                                                        int* __restrict__ idx_sel,
                                                        Ptr7 feats,
                                                        const float* __restrict__ awq,
                                                        const float* __restrict__ abq,
                                                        const int* __restrict__ gatherC,
                                                        float* __restrict__ qtab) {
    __shared__ __align__(16) char smem[SMEM_MID];
    if (blockIdx.x >= NCEN * BATCH) {
        // ---------------- qproj tile ----------------
        int id = blockIdx.x - NCEN * BATCH;    // 0..895
        int rt = id & 63;                       // 64 row tiles
        int ct = (id >> 6) & 1;                 // 2 col tiles
        int v = id >> 7;                        // 7 branches
        gemm_tile64<CH, false>(smem, feats.p[v], CH, gatherC + rt * 64,
                               awq + (size_t)v * CH * CH + ct * 64, CH,
                               abq + v * CH + ct * 64,
                               qtab + ((size_t)v * (BATCH * NCEN) + rt * 64) * CH + ct * 64, CH);
        return;
    }
    // ---------------- reach + top-32 ----------------
    unsigned* adjw = (unsigned*)smem;                     // 64
    unsigned* R1 = adjw + NW;                             // 64
    unsigned* R2 = R1 + NW;                               // 64
    int* cnt = (int*)(R2 + NW);                           // 1 (+pad)
    int* lst = (int*)(smem + 1024);                       // 2048
    float* dst = (float*)(smem + 1024 + 8192);            // 2048
    float* rv = (float*)(smem + 1024 + 16384);            // 256
    int* rj = (int*)(smem + 1024 + 16384 + 1024);         // 256
    int* rp = (int*)(smem + 1024 + 16384 + 2048);         // 256
    int* sel = (int*)(smem + 1024 + 16384 + 3072);        // 32
    int s = blockIdx.x & (NCEN - 1), b = blockIdx.x >> 9, t = threadIdx.x;
    int i = fps_idx[b * NCEN + s];
    const unsigned* arow = adj + ((size_t)(b * NPTS + i)) * NW;
    if (t < NW) { adjw[t] = arow[t]; R1[t] = arow[t]; }
    if (t == 0) cnt[0] = 0;
    __syncthreads();
    if (t < NW) {
        unsigned w = adjw[t];
        while (w) { int bb = __ffs(w) - 1; w &= w - 1; int p = atomicAdd(cnt, 1); lst[p] = t * 32 + bb; }
    }
    __syncthreads();
    int n1 = cnt[0];
    {
        int g = t >> 6, lane = t & 63;
        for (int p = g; p < n1; p += 4) {
            unsigned aw = adj[((size_t)(b * NPTS + lst[p])) * NW + lane];
            atomicOr(&R1[lane], aw);
        }
    }
    __syncthreads();
    if (t == 0) cnt[0] = 0;
    __syncthreads();
    if (t < NW) {
        unsigned w = R1[t];
        while (w) { int bb = __ffs(w) - 1; w &= w - 1; int p = atomicAdd(cnt, 1); lst[p] = t * 32 + bb; }
        R2[t] = adjw[t];
    }
    __syncthreads();
    int n2 = cnt[0];
    {
        int g = t >> 6, lane = t & 63;
        for (int p = g; p < n2; p += 4) {
            unsigned aw = adj[((size_t)(b * NPTS + lst[p])) * NW + lane];
            atomicOr(&R2[lane], aw);
        }
    }
    __syncthreads();
    if (t == 0) cnt[0] = 0;
    __syncthreads();
    const float* Dr = D + (size_t)(b * NPTS + i) * NPTS;
    if (t < NW) {
        unsigned w = R2[t];
        while (w) {
            int bb = __ffs(w) - 1; w &= w - 1;
            int j = t * 32 + bb;
            int p = atomicAdd(cnt, 1);
            lst[p] = j; dst[p] = Dr[j];
        }
    }
    __syncthreads();
    int L = cnt[0];
    int nsel = L < NNEI ? L : NNEI;
    for (int r = 0; r < nsel; r++) {
        float bv = INFINITY; int bj = 0x7fffffff, bp = -1;
        for (int p = t; p < L; p += 256) {
            float v = dst[p]; int j = lst[p];
            if (v < bv || (v == bv && j < bj)) { bv = v; bj = j; bp = p; }
        }
        rv[t] = bv; rj[t] = bj; rp[t] = bp;
        __syncthreads();
        for (int off = 128; off > 0; off >>= 1) {
            if (t < off) {
                if (rv[t + off] < rv[t] || (rv[t + off] == rv[t] && rj[t + off] < rj[t])) {
                    rv[t] = rv[t + off]; rj[t] = rj[t + off]; rp[t] = rp[t + off];
                }
            }
            __syncthreads();
        }
        if (t == 0) { sel[r] = rj[0]; dst[rp[0]] = INFINITY; }
        __syncthreads();
    }
    if (t == 0 && nsel < NNEI) {
        int r = nsel;
        for (int j = 0; j < NPTS && r < NNEI; j++)
            if (!((R2[j >> 5] >> (j & 31)) & 1)) sel[r++] = j;
    }
    __syncthreads();
    if (t < NNEI) idx_sel[((size_t)(b * NCEN + s)) * NNEI + t] = sel[t];
}

// ---------------------------------------------------------------- GEMM wrappers
__global__ __launch_bounds__(256) void kvproj_kernel(Ptr7 feats, const float* __restrict__ awk,
                                                     const float* __restrict__ abk,
                                                     const float* __restrict__ awv,
                                                     const float* __restrict__ abv,
                                                     float* __restrict__ ktab,
                                                     float* __restrict__ vtab) {
    __shared__ __align__(16) char smem[SMEM_BYTES];
    int v = blockIdx.z, ct = blockIdx.y, rt = blockIdx.x;
    bool isv = ct >= 2;
    int c2 = ct & 1;
    const float* A = feats.p[v] + (size_t)rt * 64 * CH;
    const float* W = (isv ? awv : awk) + (size_t)v * CH * CH + c2 * 64;
    const float* bias = (isv ? abv : abk) + v * CH + c2 * 64;
    float* Out = (isv ? vtab : ktab) + (size_t)v * (BATCH * NPTS) * CH + (size_t)rt * 64 * CH + c2 * 64;
    gemm_tile64<CH, false>(smem, A, CH, nullptr, W, CH, bias, Out, CH);
}

__global__ __launch_bounds__(256) void mlp1_kernel(const float* __restrict__ otab,
                                                   const float* __restrict__ mw1,
                                                   const float* __restrict__ mb1,
                                                   float* __restrict__ htab) {
    __shared__ __align__(16) char smem[SMEM_BYTES];
    int v = blockIdx.z, ct = blockIdx.y, rt = blockIdx.x;
    gemm_tile64<CH, true>(smem, otab + ((size_t)v * (BATCH * NCEN) + rt * 64) * CH, CH, nullptr,
                          mw1 + (size_t)v * CH * CHO + ct * 64, CHO,
                          mb1 + v * CHO + ct * 64,
                          htab + ((size_t)v * (BATCH * NCEN) + rt * 64) * CHO + ct * 64, CHO);
}

__global__ __launch_bounds__(256) void mlp2_kernel(const float* __restrict__ htab,
                                                   const float* __restrict__ mw2,
                                                   const float* __restrict__ mb2,
                                                   float* __restrict__ out) {
    __shared__ __align__(16) char smem[SMEM_BYTES];
    int v = blockIdx.z, ct = blockIdx.y, rt = blockIdx.x;
    gemm_tile64<CHO, true>(smem, htab + ((size_t)v * (BATCH * NCEN) + rt * 64) * CHO, CHO, nullptr,
                           mw2 + (size_t)v * CHO * CHO + ct * 64, CHO,
                           mb2 + v * CHO + ct * 64,
                           out + ((size_t)v * (BATCH * NCEN) + rt * 64) * CHO + ct * 64, CHO);
}

// ---------------------------------------------------------------- attention
__global__ __launch_bounds__(256) void attn_kernel(const float* __restrict__ qtab,
                                                   const float* __restrict__ ktab,
                                                   const float* __restrict__ vtab,
                                                   const int* __restrict__ idx_sel,
                                                   float* __restrict__ otab) {
    __shared__ float q_s[4][CH];
    __shared__ float attn_s[4][NNEI];
    __shared__ int jj_s[4][NNEI];
    int v = blockIdx.y;
    int t = threadIdx.x, w = t >> 6, lane = t & 63;
    int cg = blockIdx.x * 4 + w;
    int b = cg >> 9, s = cg & 511;
    const float* qr = qtab + ((size_t)v * (BATCH * NCEN) + cg) * CH;
    *(float2*)&q_s[w][lane * 2] = *(const float2*)(qr + lane * 2);
    if (lane < NNEI) jj_s[w][lane] = idx_sel[((size_t)(b * NCEN + s)) * NNEI + lane];
    __syncthreads();
    if (lane < NNEI) {
        int j = jj_s[w][lane];
        const float* kr = ktab + ((size_t)v * (BATCH * NPTS) + b * NPTS + j) * CH;
        float acc = 0.f;
#pragma unroll
        for (int c4 = 0; c4 < CH / 4; c4++) {
            float4 qv = *(const float4*)&q_s[w][c4 * 4];
            float4 kv = *(const float4*)(kr + c4 * 4);
            acc += qv.x * kv.x + qv.y * kv.y + qv.z * kv.z + qv.w * kv.w;
        }
        float sc = acc * 0.08838834764831845f;  // 1/sqrt(128)
        float m = sc;
#pragma unroll
        for (int off = 16; off > 0; off >>= 1) m = fmaxf(m, __shfl_xor(m, off, 32));
        float e = expf(sc - m);
        float sum = e;
#pragma unroll
        for (int off = 16; off > 0; off >>= 1) sum += __shfl_xor(sum, off, 32);
        attn_s[w][lane] = e / sum;
    }
    __syncthreads();
    float2 o = {0.f, 0.f};
    const float* vbase = vtab + ((size_t)v * (BATCH * NPTS) + b * NPTS) * CH;
    for (int tt = 0; tt < NNEI; tt++) {
        int j = jj_s[w][tt];
        float a = attn_s[w][tt];
        float2 vv = *(const float2*)(vbase + (size_t)j * CH + lane * 2);
        o.x += a * vv.x;
        o.y += a * vv.y;
    }
    *(float2*)(otab + ((size_t)v * (BATCH * NCEN) + cg) * CH + lane * 2) = o;
}

// ---------------------------------------------------------------- launch
extern "C" void kernel_launch(void* const* d_in, const int* in_sizes, int n_in,
                              void* d_out, int out_size, void* d_ws, size_t ws_size,
                              hipStream_t stream) {
    (void)in_sizes; (void)n_in; (void)out_size;
    Ptr7 feats;
    for (int i = 0; i < 7; i++) feats.p[i] = (const float*)d_in[i];
    const float* awq = (const float*)d_in[7];
    const float* abq = (const float*)d_in[8];
    const float* awk = (const float*)d_in[9];
    const float* abk = (const float*)d_in[10];
    const float* awv = (const float*)d_in[11];
    const float* abv = (const float*)d_in[12];
    const float* mw1 = (const float*)d_in[13];
    const float* mb1 = (const float*)d_in[14];
    const float* mw2 = (const float*)d_in[15];
    const float* mb2 = (const float*)d_in[16];
    const float* xyz = feats.p[0];

    char* ws = (char*)d_ws;
    size_t SZ_D = (size_t)BATCH * NPTS * NPTS * 4;       // 134 MB
    float* D = (float*)ws;
    float* ktab = (float*)ws;                            // overlays D (dead after reach)
    float* vtab = (float*)(ws + (size_t)7 * BATCH * NPTS * CH * 4);
    size_t off = SZ_D;
    float* xx = (float*)(ws + off); off += (size_t)BATCH * NPTS * 4;
    unsigned* adjb = (unsigned*)(ws + off); off += (size_t)BATCH * NPTS * NW * 4;
    int* fpsidx = (int*)(ws + off); off += (size_t)BATCH * NCEN * 4;
    int* idxsel = (int*)(ws + off); off += (size_t)BATCH * NCEN * NNEI * 4;
    int* gatherC = (int*)(ws + off); off += (size_t)BATCH * NCEN * 4;
    float* qtab = (float*)(ws + off); off += (size_t)7 * BATCH * NCEN * CH * 4;
    float* otab = (float*)(ws + off); off += (size_t)7 * BATCH * NCEN * CH * 4;
    float* htab = (float*)(ws + off); off += (size_t)7 * BATCH * NCEN * CHO * 4;
    if (ws_size < off) return;

    xx_kernel<<<dim3((BATCH * NPTS + 255) / 256), dim3(256), 0, stream>>>(xyz, xx);
    dmat_kernel<<<dim3(NPTS / 64, NPTS / 64, BATCH), dim3(256), 0, stream>>>(xyz, xx, D);
    fused_front_kernel<<<dim3(BATCH + BATCH * NPTS), dim3(256), 0, stream>>>(D, adjb, fpsidx);
    make_gather<<<dim3((BATCH * NCEN + 255) / 256), dim3(256), 0, stream>>>(fpsidx, gatherC);
    fused_mid_kernel<<<dim3(NCEN * BATCH + 2 * 7 * (BATCH * NCEN / 64)), dim3(256), 0, stream>>>(
        adjb, D, fpsidx, idxsel, feats, awq, abq, gatherC, qtab);
    // D dead: ktab/vtab overlay it
    kvproj_kernel<<<dim3(BATCH * NPTS / 64, 4, 7), dim3(256), 0, stream>>>(feats, awk, abk, awv, abv, ktab, vtab);
    attn_kernel<<<dim3(BATCH * NCEN / 4, 7), dim3(256), 0, stream>>>(qtab, ktab, vtab, idxsel, otab);
    mlp1_kernel<<<dim3(BATCH * NCEN / 64, 4, 7), dim3(256), 0, stream>>>(otab, mw1, mb1, htab);
    mlp2_kernel<<<dim3(BATCH * NCEN / 64, 4, 7), dim3(256), 0, stream>>>(htab, mw2, mb2, (float*)d_out);
}